// Round 9
// baseline (299.566 us; speedup 1.0000x reference)
//
#include <hip/hip_runtime.h>
#include <hip/hip_bf16.h>
#include <math.h>

typedef __bf16 bf16;
typedef __attribute__((ext_vector_type(8))) __bf16 bf16x8;
typedef __attribute__((ext_vector_type(4))) __bf16 bf16x4;
typedef __attribute__((ext_vector_type(4))) float f32x4;

#define D_DIM 2048
#define NKV   576

__device__ inline void gld_lds16(const void* g, void* l) {
    void* gg = const_cast<void*>(g);
    __builtin_amdgcn_global_load_lds(
        (__attribute__((address_space(1))) void*)gg,
        (__attribute__((address_space(3))) void*)l, 16, 0, 0);
}

#define PH_BARRIER() do { __builtin_amdgcn_s_barrier(); asm volatile("" ::: "memory"); } while (0)
#define VMCNT(n)     asm volatile("s_waitcnt vmcnt(" #n ")" ::: "memory")

// ---------------------------------------------------------------------------
// prep: blocks 0..4095 = weight cast+transpose; 4096..9343 = rmsnorm+cast
// ---------------------------------------------------------------------------
__global__ __launch_bounds__(256) void prep(
    const float* __restrict__ hidden, const float* __restrict__ wsp,
    const float* __restrict__ corr, const float* __restrict__ lnq,
    const float* __restrict__ lnkv,
    const float* __restrict__ Wq, const float* __restrict__ Wk,
    const float* __restrict__ Wv, const float* __restrict__ Wo,
    bf16* __restrict__ hb, bf16* __restrict__ kvb,
    bf16* __restrict__ WqT, bf16* __restrict__ WkvT, bf16* __restrict__ WoT)
{
    __shared__ float tl[64][65];
    __shared__ float p[4];
    const int id = blockIdx.x, t = threadIdx.x;

    if (id < 4096) {
        const int wz = id >> 10, idx = id & 1023;
        const int wy = idx >> 5, wx = idx & 31;
        const float* in; bf16* out;
        switch (wz) {
            case 0:  in = Wq; out = WqT; break;
            case 1:  in = Wk; out = WkvT; break;
            case 2:  in = Wv; out = WkvT + 2048ull * 2048; break;
            default: in = Wo; out = WoT; break;
        }
        const int r0 = wy * 64, c0 = wx * 64;
        const int tr = t >> 4, tc = (t & 15) * 4;
#pragma unroll
        for (int q = 0; q < 4; ++q) {
            const int r = tr + q * 16;
            float4 v = *(const float4*)(in + (long)(r0 + r) * 2048 + c0 + tc);
            tl[r][tc] = v.x; tl[r][tc + 1] = v.y;
            tl[r][tc + 2] = v.z; tl[r][tc + 3] = v.w;
        }
        __syncthreads();
#pragma unroll
        for (int q = 0; q < 2; ++q) {
            const int rc = (t >> 3) + q * 32;     // output row (c-dim) 0..63
            const int c8 = (t & 7) * 8;
            bf16x8 o;
#pragma unroll
            for (int i = 0; i < 8; ++i) o[i] = (bf16)tl[c8 + i][rc];
            *(bf16x8*)(out + (long)(c0 + rc) * 2048 + r0 + c8) = o;
        }
        return;
    }

    const int rr0 = id - 4096;
    const float* xr; const float* w; bf16* yr;
    if (rr0 < 4096) {
        xr = hidden + (long)rr0 * D_DIM; w = lnq; yr = hb + (long)rr0 * D_DIM;
    } else if (rr0 < 4224) {
        const int rr = rr0 - 4096;
        xr = wsp + (long)rr * D_DIM; w = lnkv;
        yr = kvb + ((long)(rr >> 6) * NKV + (rr & 63)) * D_DIM;
    } else {
        const int rr = rr0 - 4224;
        xr = corr + (long)rr * D_DIM; w = lnkv;
        yr = kvb + ((long)(rr >> 9) * NKV + 64 + (rr & 511)) * D_DIM;
    }

    float4 v0 = *(const float4*)(xr + t * 4);
    float4 v1 = *(const float4*)(xr + 1024 + t * 4);
    float ss = v0.x * v0.x + v0.y * v0.y + v0.z * v0.z + v0.w * v0.w
             + v1.x * v1.x + v1.y * v1.y + v1.z * v1.z + v1.w * v1.w;
#pragma unroll
    for (int off = 32; off; off >>= 1) ss += __shfl_xor(ss, off);
    if ((t & 63) == 0) p[t >> 6] = ss;
    __syncthreads();
    const float rs = rsqrtf((p[0] + p[1] + p[2] + p[3]) * (1.0f / 2048.0f) + 1e-6f);

    float4 w0 = *(const float4*)(w + t * 4);
    float4 w1 = *(const float4*)(w + 1024 + t * 4);
    bf16x4 o0 = { (bf16)(v0.x * rs * w0.x), (bf16)(v0.y * rs * w0.y),
                  (bf16)(v0.z * rs * w0.z), (bf16)(v0.w * rs * w0.w) };
    bf16x4 o1 = { (bf16)(v1.x * rs * w1.x), (bf16)(v1.y * rs * w1.y),
                  (bf16)(v1.z * rs * w1.z), (bf16)(v1.w * rs * w1.w) };
    *(bf16x4*)(yr + t * 4) = o0;
    *(bf16x4*)(yr + 1024 + t * 4) = o1;
}

// ---------------------------------------------------------------------------
// Fused Q + KV projections. (unchanged from R5/R7 — deep-pipeline 8-phase)
// ---------------------------------------------------------------------------
__global__ __launch_bounds__(512, 2) void proj_all(
    const bf16* __restrict__ hb, const bf16* __restrict__ kvb,
    const bf16* __restrict__ WqT, const bf16* __restrict__ WkvT,
    bf16* __restrict__ qb, bf16* __restrict__ kb, bf16* __restrict__ vtb)
{
    __shared__ __align__(16) bf16 smem[4][16384];   // EA,EB,OA,OB = 128 KiB
    bf16* const EA = smem[0]; bf16* const EB = smem[1];
    bf16* const OA = smem[2]; bf16* const OB = smem[3];

    const int id0 = blockIdx.x;
    const int id = (id0 & 7) * 26 + (id0 >> 3);     // bijective: 208 = 8*26
    const bf16 *A, *B; int m0, n0; bool isQ;
    if (id < 128) {
        isQ = true;  A = hb;  B = WqT;
        m0 = (id >> 3) * 256; n0 = (id & 7) * 256;
    } else {
        const int kd = id - 128;
        isQ = false; A = kvb; B = WkvT;
        m0 = (kd >> 4) * 256; n0 = (kd & 15) * 256;
    }

    const int tid = threadIdx.x, lane = tid & 63, w = tid >> 6;
    const int wm = (w >> 2) * 128, wn = (w & 3) * 64;
    const int fr = lane & 15, fg = lane >> 4;

    f32x4 acc[8][4] = {};
    bf16x8 af[4][2], bg[4][2];

    const int aoff0 = (wm + fr) * 64 + (fg ^ (fr & 7)) * 8;
    const int boff0 = (wn + fr) * 64 + (fg ^ (fr & 7)) * 8;
    const int aoff1 = aoff0 ^ 32, boff1 = boff0 ^ 32;
    const bf16* const pAE[2] = { EA + aoff0, EA + aoff1 };
    const bf16* const pAO[2] = { OA + aoff0, OA + aoff1 };
    const bf16* const pBE[2] = { EB + boff0, EB + boff1 };
    const bf16* const pBO[2] = { OB + boff0, OB + boff1 };

    const long toff = (long)(tid >> 3) * 2048 + (((tid & 7) ^ ((tid >> 3) & 7)) * 8);
    const bf16* const gA0 = A + (long)m0 * 2048 + toff;
    const bf16* const gA1 = gA0 + 262144;           // +128 rows
    const bf16* const gB0 = B + (long)n0 * 2048 + toff;
    const bf16* const gB1 = gB0 + 262144;
    bf16* const dT = (bf16*)smem + tid * 8;

    auto stage2 = [&](const bf16* g, int k, int dslot) {
        gld_lds16(g + k, dT + dslot);
        gld_lds16(g + 131072 + k, dT + dslot + 4096);
    };
    enum { sEA0 = 0, sEA1 = 8192, sEB0 = 16384, sEB1 = 24576,
           sOA0 = 32768, sOA1 = 40960, sOB0 = 49152, sOB1 = 57344 };

    auto load_af = [&](const bf16* const p[2], int ib) {
#pragma unroll
        for (int i = 0; i < 4; ++i)
#pragma unroll
            for (int s = 0; s < 2; ++s)
                af[i][s] = *(const bf16x8*)(p[s] + (ib + i) * 1024);
    };
    auto load_bg4 = [&](const bf16* const p[2]) {
#pragma unroll
        for (int j = 0; j < 4; ++j)
#pragma unroll
            for (int s = 0; s < 2; ++s)
                bg[j][s] = *(const bf16x8*)(p[s] + j * 1024);
    };
    auto mfma16 = [&](int ib, int jb) {
        __builtin_amdgcn_s_setprio(1);
#pragma unroll
        for (int s = 0; s < 2; ++s)
#pragma unroll
            for (int i = 0; i < 4; ++i)
#pragma unroll
                for (int j = 0; j < 2; ++j)
                    acc[ib + i][jb + j] = __builtin_amdgcn_mfma_f32_16x16x32_bf16(
                        af[i][s], bg[jb + j][s], acc[ib + i][jb + j], 0, 0, 0);
        __builtin_amdgcn_s_setprio(0);
    };

    stage2(gA0, 0, sEA0); stage2(gA1, 0, sEA1);
    stage2(gB0, 0, sEB0); stage2(gB1, 0, sEB1);
    stage2(gB0, 64, sOB0); stage2(gB1, 64, sOB1);
    stage2(gA0, 64, sOA0);
    VMCNT(6);
    PH_BARRIER();

    for (int it = 0; it < 15; ++it) {
        const int kO = it * 128 + 64, kE2 = it * 128 + 128, kO2 = it * 128 + 192;
        load_af(pAE, 0); load_bg4(pBE);
        stage2(gA1, kO, sOA1);
        PH_BARRIER(); mfma16(0, 0); PH_BARRIER();
        stage2(gB0, kE2, sEB0);
        PH_BARRIER(); mfma16(0, 2); PH_BARRIER();
        load_af(pAE, 4);
        stage2(gB1, kE2, sEB1);
        PH_BARRIER(); mfma16(4, 2); PH_BARRIER();
        stage2(gA0, kE2, sEA0);
        PH_BARRIER(); mfma16(4, 0); VMCNT(6); PH_BARRIER();
        load_af(pAO, 0); load_bg4(pBO);
        stage2(gA1, kE2, sEA1);
        PH_BARRIER(); mfma16(0, 0); PH_BARRIER();
        stage2(gB0, kO2, sOB0);
        PH_BARRIER(); mfma16(0, 2); PH_BARRIER();
        load_af(pAO, 4);
        stage2(gB1, kO2, sOB1);
        PH_BARRIER(); mfma16(4, 2); PH_BARRIER();
        stage2(gA0, kO2, sOA0);
        PH_BARRIER(); mfma16(4, 0); VMCNT(6); PH_BARRIER();
    }
    {
        load_af(pAE, 0); load_bg4(pBE);
        stage2(gA1, 1984, sOA1);
        PH_BARRIER(); mfma16(0, 0); PH_BARRIER();
        PH_BARRIER(); mfma16(0, 2); PH_BARRIER();
        load_af(pAE, 4);
        PH_BARRIER(); mfma16(4, 2); PH_BARRIER();
        PH_BARRIER(); mfma16(4, 0); VMCNT(0); PH_BARRIER();
        load_af(pAO, 0); load_bg4(pBO);
        PH_BARRIER(); mfma16(0, 0); PH_BARRIER();
        PH_BARRIER(); mfma16(0, 2); PH_BARRIER();
        load_af(pAO, 4);
        PH_BARRIER(); mfma16(4, 2); PH_BARRIER();
        PH_BARRIER(); mfma16(4, 0); PH_BARRIER();
    }

    __syncthreads();

    const int er = fg * 4;
    if (isQ || n0 < 2048) {
        bf16* C = isQ ? qb : kb;
        const int mlim = isQ ? 4096 : 1152;
#pragma unroll
        for (int i = 0; i < 8; ++i)
#pragma unroll
            for (int j = 0; j < 4; ++j) {
                const int n = n0 + wn + j * 16 + fr;
#pragma unroll
                for (int r = 0; r < 4; ++r) {
                    const int m = m0 + wm + i * 16 + er + r;
                    if (m < mlim)
                        C[(long)m * 2048 + n] = (bf16)acc[i][j][r];
                }
            }
        return;
    }

    bf16* T = &smem[0][0];                 // [128][264]
#pragma unroll
    for (int p2 = 0; p2 < 2; ++p2) {
        if (p2) __syncthreads();
        if ((wn >> 7) == p2) {
            const int nb = wn - p2 * 128;
#pragma unroll
            for (int i = 0; i < 8; ++i)
#pragma unroll
                for (int j = 0; j < 4; ++j) {
                    const int nl = nb + j * 16 + fr;
#pragma unroll
                    for (int r = 0; r < 4; ++r)
                        T[nl * 264 + wm + i * 16 + er + r] = (bf16)acc[i][j][r];
                }
        }
        __syncthreads();
        const int hh = (n0 - 2048 + p2 * 128) >> 7;
        for (int e = tid; e < 128 * 64; e += 512) {
            const int d = e >> 6, mg = (e & 63) * 4;
            const int mm = m0 + mg;
            if (mm < 1152) {
                bf16x4 val = *(const bf16x4*)(T + d * 264 + mg);
                const int bb = mm >= NKV;
                const int s = mm - bb * NKV;
                *(bf16x4*)(vtb + ((long)((bb * 16 + hh) * 128 + d)) * NKV + s) = val;
            }
        }
    }
}

// ---------------------------------------------------------------------------
// Final GEMM: out(4096x2048 fp32) = aob @ WoT^T. (unchanged from R5/R7)
// ---------------------------------------------------------------------------
__global__ __launch_bounds__(512, 2) void gemm_final(
    const bf16* __restrict__ Ag, const bf16* __restrict__ Bg, float* __restrict__ C)
{
    __shared__ __align__(16) bf16 smem[49152];
    bf16* const EA = smem;           bf16* const EB = smem + 16384;
    bf16* const OA = smem + 24576;   bf16* const OB = smem + 40960;

    const int id0 = blockIdx.x;
    const int id = (id0 & 7) * 32 + (id0 >> 3);    // 256 = 8*32
    const int m0 = (id >> 4) * 256, n0 = (id & 15) * 128;

    const int tid = threadIdx.x, lane = tid & 63, w = tid >> 6;
    const int wm = (w >> 1) * 64, wn = (w & 1) * 64;
    const int fr = lane & 15, fg = lane >> 4;

    f32x4 acc[4][4] = {};
    bf16x8 af[2][2], bg[4][2];

    const int aoff0 = (wm + fr) * 64 + (fg ^ (fr & 7)) * 8;
    const int boff0 = (wn + fr) * 64 + (fg ^ (fr & 7)) * 8;
    const int aoff1 = aoff0 ^ 32, boff1 = boff0 ^ 32;
    const bf16* const pAE[2] = { EA + aoff0, EA + aoff1 };
    const bf16* const pAO[2] = { OA + aoff0, OA + aoff1 };
    const bf16* const pBE[2] = { EB + boff0, EB + boff1 };
    const bf16* const pBO[2] = { OB + boff0, OB + boff1 };

    const long toff = (long)(tid >> 3) * 2048 + (((tid & 7) ^ ((tid >> 3) & 7)) * 8);
    const bf16* const gA0 = Ag + (long)m0 * 2048 + toff;
    const bf16* const gA1 = gA0 + 262144;
    const bf16* const gB0 = Bg + (long)n0 * 2048 + toff;
    bf16* const dT = smem + tid * 8;

    auto stage2 = [&](const bf16* g, int k, int dslot) {
        gld_lds16(g + k, dT + dslot);
        gld_lds16(g + 131072 + k, dT + dslot + 4096);
    };
    enum { sEA0 = 0, sEA1 = 8192, sEB0 = 16384,
           sOA0 = 24576, sOA1 = 32768, sOB0 = 40960 };

    auto load_af = [&](const bf16* const p[2], int ib) {
#pragma unroll
        for (int i = 0; i < 2; ++i)
#pragma unroll
            for (int s = 0; s < 2; ++s)
                af[i][s] = *(const bf16x8*)(p[s] + (ib + i) * 1024);
    };
    auto load_bg4 = [&](const bf16* const p[2]) {
#pragma unroll
        for (int j = 0; j < 4; ++j)
#pragma unroll
            for (int s = 0; s < 2; ++s)
                bg[j][s] = *(const bf16x8*)(p[s] + j * 1024);
    };
    auto mfma8 = [&](int ib, int jb) {
        __builtin_amdgcn_s_setprio(1);
#pragma unroll
        for (int s = 0; s < 2; ++s)
#pragma unroll
            for (int i = 0; i < 2; ++i)
#pragma unroll
                for (int j = 0; j < 2; ++j)
                    acc[ib + i][jb + j] = __builtin_amdgcn_mfma_f32_16x16x32_bf16(
                        af[i][s], bg[jb + j][s], acc[ib + i][jb + j], 0, 0, 0);
        __builtin_amdgcn_s_setprio(0);
    };

    stage2(gA0, 0, sEA0); stage2(gA1, 0, sEA1);
    stage2(gB0, 0, sEB0);
    stage2(gB0, 64, sOB0); stage2(gA0, 64, sOA0);
    VMCNT(4);
    PH_BARRIER();

    for (int it = 0; it < 15; ++it) {
        const int kO = it * 128 + 64, kE2 = it * 128 + 128, kO2 = it * 128 + 192;
        load_af(pAE, 0); load_bg4(pBE);
        stage2(gA1, kO, sOA1);
        PH_BARRIER(); mfma8(0, 0); PH_BARRIER();
        stage2(gB0, kE2, sEB0);
        PH_BARRIER(); mfma8(0, 2); PH_BARRIER();
        load_af(pAE, 2);
        PH_BARRIER(); mfma8(2, 2); PH_BARRIER();
        stage2(gA0, kE2, sEA0);
        PH_BARRIER(); mfma8(2, 0); VMCNT(4); PH_BARRIER();
        load_af(pAO, 0); load_bg4(pBO);
        stage2(gA1, kE2, sEA1);
        PH_BARRIER(); mfma8(0, 0); PH_BARRIER();
        stage2(gB0, kO2, sOB0);
        PH_BARRIER(); mfma8(0, 2); PH_BARRIER();
        load_af(pAO, 2);
        PH_BARRIER(); mfma8(2, 2); PH_BARRIER();
        stage2(gA0, kO2, sOA0);
        PH_BARRIER(); mfma8(2, 0); VMCNT(4); PH_BARRIER();
    }
    {
        load_af(pAE, 0); load_bg4(pBE);
        stage2(gA1, 1984, sOA1);
        PH_BARRIER(); mfma8(0, 0); PH_BARRIER();
        PH_BARRIER(); mfma8(0, 2); PH_BARRIER();
        load_af(pAE, 2);
        PH_BARRIER(); mfma8(2, 2); PH_BARRIER();
        PH_BARRIER(); mfma8(2, 0); VMCNT(0); PH_BARRIER();
        load_af(pAO, 0); load_bg4(pBO);
        PH_BARRIER(); mfma8(0, 0); PH_BARRIER();
        PH_BARRIER(); mfma8(0, 2); PH_BARRIER();
        load_af(pAO, 2);
        PH_BARRIER(); mfma8(2, 2); PH_BARRIER();
        PH_BARRIER(); mfma8(2, 0); PH_BARRIER();
    }

    __syncthreads();

    const int er = fg * 4;
#pragma unroll
    for (int i = 0; i < 4; ++i)
#pragma unroll
        for (int j = 0; j < 4; ++j) {
            const int n = n0 + wn + j * 16 + fr;
#pragma unroll
            for (int r = 0; r < 4; ++r)
                C[(long)(m0 + wm + i * 16 + er + r) * 2048 + n] = acc[i][j][r];
        }
}

// ---------------------------------------------------------------------------
// Flash attention: 8 waves, q-tile 128, kv-chunk 64 (9 chunks). DOUBLE-
// BUFFERED K/V with counted vmcnt: chunk i+2's stages issue right after the
// barrier that retires chunk i's reads; VMCNT(4) drains only chunk i+1's
// stages (issued a full chunk earlier) -> no exposed HBM latency.
// LDS = Ks[2](32K) + VTs[2](32K) + Ps(16K, XOR-swizzled) = 80 KiB -> 2 blk/CU.
// grid (T/128, H, B) = (16,16,2) = 512 blocks, all resident.
// ---------------------------------------------------------------------------
__global__ __launch_bounds__(512, 4) void flash_attn(
    const bf16* __restrict__ Q, const bf16* __restrict__ K,
    const bf16* __restrict__ VT, const int* __restrict__ cmask,
    bf16* __restrict__ O)
{
    __shared__ __align__(16) bf16 Ks[2][64 * 128];   // swizzled K chunks
    __shared__ __align__(16) bf16 VTs[2][128 * 64];  // swizzled V^T chunks
    __shared__ __align__(16) bf16 Ps[128 * 64];      // P transpose, XOR-swizzled

    const int qt = blockIdx.x, h = blockIdx.y, b = blockIdx.z;
    const int tid = threadIdx.x, lane = tid & 63, w = tid >> 6;   // w: 0..7
    const int fr = lane & 15, fg = lane >> 4;

    const bf16* qbase = Q + ((long)(b * 2048 + qt * 128)) * 2048 + h * 128;
    bf16x8 qf[4];
#pragma unroll
    for (int s = 0; s < 4; ++s)
        qf[s] = *(const bf16x8*)(qbase + (long)(w * 16 + fr) * 2048 + s * 32 + fg * 8);

    float m_r[4], l_r[4];
    f32x4 acc_o[8];
#pragma unroll
    for (int r = 0; r < 4; ++r) { m_r[r] = -3.0e38f; l_r[r] = 0.f; }
#pragma unroll
    for (int j = 0; j < 8; ++j) acc_o[j] = (f32x4){0.f, 0.f, 0.f, 0.f};

    const float scale2 = 0.12752792330124195f;  // (1/sqrt(128)) * log2(e)
    const bf16* kbase = K + (long)b * NKV * 2048 + h * 128;
    const bf16* vbase = VT + ((long)(b * 16 + h)) * 128 * NKV;
    const int* const cm = cmask + b * 512;

    // stage chunk kv0 into buffer bi (2 gld_lds/thread for K, 2 for V)
    auto stageK = [&](int kv0, int bi) {
#pragma unroll
        for (int p = 0; p < 2; ++p) {
            const int c = p * 512 + tid;
            const int r = c >> 4, cs = c & 15, cl = cs ^ (r & 15);
            gld_lds16(kbase + (long)(kv0 + r) * 2048 + cl * 8, Ks[bi] + c * 8);
        }
    };
    auto stageV = [&](int kv0, int bi) {
#pragma unroll
        for (int p = 0; p < 2; ++p) {
            const int c = p * 512 + tid;
            const int r = c >> 3, cs = c & 7, cl = cs ^ (r & 7);
            gld_lds16(vbase + (long)r * NKV + kv0 + cl * 8, VTs[bi] + c * 8);
        }
    };

    // prologue: chunks 0 and 1; drain chunk 0 (leave chunk 1 in flight)
    stageK(0, 0);  stageV(0, 0);
    stageK(64, 1); stageV(64, 1);
    VMCNT(4);
    PH_BARRIER();

    for (int kc = 0; kc < 9; ++kc) {
        const int kv0 = kc * 64, cur = kc & 1;

        f32x4 acc_s[4] = {};
#pragma unroll
        for (int s = 0; s < 4; ++s) {
#pragma unroll
            for (int j = 0; j < 4; ++j) {
                bf16x8 bgv = *(const bf16x8*)(Ks[cur] +
                    ((j * 16 + fr) * 16 + ((s * 4 + fg) ^ fr)) * 8);
                acc_s[j] = __builtin_amdgcn_mfma_f32_16x16x32_bf16(qf[s], bgv, acc_s[j], 0, 0, 0);
            }
        }

        float bias[4];
#pragma unroll
        for (int j = 0; j < 4; ++j) {
            const int kv = kv0 + j * 16 + fr;
            const bool valid = (kv < 64) || (cm[kv - 64] != 0);
            bias[j] = valid ? 0.f : -1e30f;
        }
        float s_f[4][4];
        float mc[4] = {-3.0e38f, -3.0e38f, -3.0e38f, -3.0e38f};
#pragma unroll
        for (int j = 0; j < 4; ++j)
#pragma unroll
            for (int r = 0; r < 4; ++r) {
                float v = fmaf(acc_s[j][r], scale2, bias[j]);
                s_f[j][r] = v; mc[r] = fmaxf(mc[r], v);
            }
#pragma unroll
        for (int r = 0; r < 4; ++r) {
            mc[r] = fmaxf(mc[r], __shfl_xor(mc[r], 1));
            mc[r] = fmaxf(mc[r], __shfl_xor(mc[r], 2));
            mc[r] = fmaxf(mc[r], __shfl_xor(mc[r], 4));
            mc[r] = fmaxf(mc[r], __shfl_xor(mc[r], 8));
        }
        float alpha[4];
#pragma unroll
        for (int r = 0; r < 4; ++r) {
            const float mn = fmaxf(m_r[r], mc[r]);
            alpha[r] = __builtin_amdgcn_exp2f(m_r[r] - mn);
            m_r[r] = mn;
        }
        float rs[4] = {0.f, 0.f, 0.f, 0.f};
#pragma unroll
        for (int j = 0; j < 4; ++j)
#pragma unroll
            for (int r = 0; r < 4; ++r) {
                const float pv = __builtin_amdgcn_exp2f(s_f[j][r] - m_r[r]);
                s_f[j][r] = pv; rs[r] += pv;
            }
#pragma unroll
        for (int r = 0; r < 4; ++r) {
            rs[r] += __shfl_xor(rs[r], 1);
            rs[r] += __shfl_xor(rs[r], 2);
            rs[r] += __shfl_xor(rs[r], 4);
            rs[r] += __shfl_xor(rs[r], 8);
            l_r[r] = l_r[r] * alpha[r] + rs[r];
        }
#pragma unroll
        for (int j = 0; j < 8; ++j)
#pragma unroll
            for (int r = 0; r < 4; ++r) acc_o[j][r] *= alpha[r];

        // P transpose: wave-private rows, XOR-swizzled cols (bank spread).
        // write row = w*16+fg*4+r, col = (j*16+fr) ^ ((row&7)<<3)
#pragma unroll
        for (int j = 0; j < 4; ++j)
#pragma unroll
            for (int r = 0; r < 4; ++r) {
                const int row = w * 16 + fg * 4 + r;
                Ps[row * 64 + ((j * 16 + fr) ^ ((row & 7) << 3))] = (bf16)s_f[j][r];
            }

#pragma unroll
        for (int s2 = 0; s2 < 2; ++s2) {
            const int prow = w * 16 + fr;
            bf16x8 afv = *(const bf16x8*)(Ps + prow * 64 +
                ((s2 * 32 + fg * 8) ^ ((prow & 7) << 3)));
#pragma unroll
            for (int jd = 0; jd < 8; ++jd) {
                bf16x8 bgv = *(const bf16x8*)(VTs[cur] +
                    ((jd * 16 + fr) * 8 + ((s2 * 4 + fg) ^ (fr & 7))) * 8);
                acc_o[jd] = __builtin_amdgcn_mfma_f32_16x16x32_bf16(afv, bgv, acc_o[jd], 0, 0, 0);
            }
        }

        PH_BARRIER();                    // all reads of Ks[cur]/VTs[cur]/Ps done
        if (kc <= 6) {                   // stage chunk kc+2 into the freed buffers
            stageK(kv0 + 128, cur);
            stageV(kv0 + 128, cur);
            VMCNT(4);                    // drains chunk kc+1 (issued 1 chunk ago)
        } else {
            VMCNT(0);                    // tail: drain everything
        }
        PH_BARRIER();                    // entry for chunk kc+1
    }

    bf16* obase = O + ((long)(b * 2048 + qt * 128)) * 2048 + h * 128;
#pragma unroll
    for (int r = 0; r < 4; ++r) {
        const float inv = 1.0f / l_r[r];
        const int row = w * 16 + fg * 4 + r;
#pragma unroll
        for (int jd = 0; jd < 8; ++jd)
            obase[(long)row * 2048 + jd * 16 + fr] = (bf16)(acc_o[jd][r] * inv);
    }
}

// ---------------------------------------------------------------------------
extern "C" void kernel_launch(void* const* d_in, const int* in_sizes, int n_in,
                              void* d_out, int out_size, void* d_ws, size_t ws_size,
                              hipStream_t stream)
{
    const float* hidden = (const float*)d_in[0];
    const float* wsp    = (const float*)d_in[1];
    const float* corr   = (const float*)d_in[2];
    const int*   cmask  = (const int*)d_in[3];
    const float* lnq    = (const float*)d_in[4];
    const float* lnkv   = (const float*)d_in[5];
    const float* Wq     = (const float*)d_in[6];
    const float* Wk     = (const float*)d_in[7];
    const float* Wv     = (const float*)d_in[8];
    const float* Wo     = (const float*)d_in[9];
    float* out = (float*)d_out;

    char* ws = (char*)d_ws;
    size_t off = 0;
    auto alloc = [&](size_t sz) { void* p = ws + off; off += (sz + 255) & ~(size_t)255; return p; };

    bf16* WqT   = (bf16*)alloc(2048ull * 2048 * 2);
    bf16* WkvT  = (bf16*)alloc(4096ull * 2048 * 2);   // [WkT ; WvT]
    bf16* WoT   = (bf16*)alloc(2048ull * 2048 * 2);
    bf16* hb    = (bf16*)alloc(4096ull * 2048 * 2);
    bf16* kvb   = (bf16*)alloc(1280ull * 2048 * 2);   // padded to 1280 rows
    bf16* qb    = (bf16*)alloc(4096ull * 2048 * 2);
    bf16* kb    = (bf16*)alloc(1152ull * 2048 * 2);   // K (B,576,2048)
    bf16* vtb   = (bf16*)alloc(4096ull * NKV * 2);    // V^T (B,H,128,576)
    bf16* aob   = (bf16*)alloc(4096ull * 2048 * 2);

    prep<<<9344, 256, 0, stream>>>(hidden, wsp, corr, lnq, lnkv,
                                   Wq, Wk, Wv, Wo, hb, kvb, WqT, WkvT, WoT);
    proj_all<<<208, 512, 0, stream>>>(hb, kvb, WqT, WkvT, qb, kb, vtb);
    flash_attn<<<dim3(16, 16, 2), 512, 0, stream>>>(qb, kb, vtb, cmask, aob);
    gemm_final<<<256, 512, 0, stream>>>(aob, WoT, out);
}

// Round 10
// 287.071 us; speedup vs baseline: 1.0435x; 1.0435x over previous
//
#include <hip/hip_runtime.h>
#include <hip/hip_bf16.h>
#include <math.h>

typedef __bf16 bf16;
typedef __attribute__((ext_vector_type(8))) __bf16 bf16x8;
typedef __attribute__((ext_vector_type(4))) __bf16 bf16x4;
typedef __attribute__((ext_vector_type(4))) float f32x4;

#define D_DIM 2048
#define NKV   576

__device__ inline void gld_lds16(const void* g, void* l) {
    void* gg = const_cast<void*>(g);
    __builtin_amdgcn_global_load_lds(
        (__attribute__((address_space(1))) void*)gg,
        (__attribute__((address_space(3))) void*)l, 16, 0, 0);
}

#define PH_BARRIER() do { __builtin_amdgcn_s_barrier(); asm volatile("" ::: "memory"); } while (0)
#define VMCNT(n)     asm volatile("s_waitcnt vmcnt(" #n ")" ::: "memory")

// ---------------------------------------------------------------------------
// prep: blocks 0..4095 = weight cast+transpose; 4096..9343 = rmsnorm+cast
// ---------------------------------------------------------------------------
__global__ __launch_bounds__(256) void prep(
    const float* __restrict__ hidden, const float* __restrict__ wsp,
    const float* __restrict__ corr, const float* __restrict__ lnq,
    const float* __restrict__ lnkv,
    const float* __restrict__ Wq, const float* __restrict__ Wk,
    const float* __restrict__ Wv, const float* __restrict__ Wo,
    bf16* __restrict__ hb, bf16* __restrict__ kvb,
    bf16* __restrict__ WqT, bf16* __restrict__ WkvT, bf16* __restrict__ WoT)
{
    __shared__ float tl[64][65];
    __shared__ float p[4];
    const int id = blockIdx.x, t = threadIdx.x;

    if (id < 4096) {
        const int wz = id >> 10, idx = id & 1023;
        const int wy = idx >> 5, wx = idx & 31;
        const float* in; bf16* out;
        switch (wz) {
            case 0:  in = Wq; out = WqT; break;
            case 1:  in = Wk; out = WkvT; break;
            case 2:  in = Wv; out = WkvT + 2048ull * 2048; break;
            default: in = Wo; out = WoT; break;
        }
        const int r0 = wy * 64, c0 = wx * 64;
        const int tr = t >> 4, tc = (t & 15) * 4;
#pragma unroll
        for (int q = 0; q < 4; ++q) {
            const int r = tr + q * 16;
            float4 v = *(const float4*)(in + (long)(r0 + r) * 2048 + c0 + tc);
            tl[r][tc] = v.x; tl[r][tc + 1] = v.y;
            tl[r][tc + 2] = v.z; tl[r][tc + 3] = v.w;
        }
        __syncthreads();
#pragma unroll
        for (int q = 0; q < 2; ++q) {
            const int rc = (t >> 3) + q * 32;     // output row (c-dim) 0..63
            const int c8 = (t & 7) * 8;
            bf16x8 o;
#pragma unroll
            for (int i = 0; i < 8; ++i) o[i] = (bf16)tl[c8 + i][rc];
            *(bf16x8*)(out + (long)(c0 + rc) * 2048 + r0 + c8) = o;
        }
        return;
    }

    const int rr0 = id - 4096;
    const float* xr; const float* w; bf16* yr;
    if (rr0 < 4096) {
        xr = hidden + (long)rr0 * D_DIM; w = lnq; yr = hb + (long)rr0 * D_DIM;
    } else if (rr0 < 4224) {
        const int rr = rr0 - 4096;
        xr = wsp + (long)rr * D_DIM; w = lnkv;
        yr = kvb + ((long)(rr >> 6) * NKV + (rr & 63)) * D_DIM;
    } else {
        const int rr = rr0 - 4224;
        xr = corr + (long)rr * D_DIM; w = lnkv;
        yr = kvb + ((long)(rr >> 9) * NKV + 64 + (rr & 511)) * D_DIM;
    }

    float4 v0 = *(const float4*)(xr + t * 4);
    float4 v1 = *(const float4*)(xr + 1024 + t * 4);
    float ss = v0.x * v0.x + v0.y * v0.y + v0.z * v0.z + v0.w * v0.w
             + v1.x * v1.x + v1.y * v1.y + v1.z * v1.z + v1.w * v1.w;
#pragma unroll
    for (int off = 32; off; off >>= 1) ss += __shfl_xor(ss, off);
    if ((t & 63) == 0) p[t >> 6] = ss;
    __syncthreads();
    const float rs = rsqrtf((p[0] + p[1] + p[2] + p[3]) * (1.0f / 2048.0f) + 1e-6f);

    float4 w0 = *(const float4*)(w + t * 4);
    float4 w1 = *(const float4*)(w + 1024 + t * 4);
    bf16x4 o0 = { (bf16)(v0.x * rs * w0.x), (bf16)(v0.y * rs * w0.y),
                  (bf16)(v0.z * rs * w0.z), (bf16)(v0.w * rs * w0.w) };
    bf16x4 o1 = { (bf16)(v1.x * rs * w1.x), (bf16)(v1.y * rs * w1.y),
                  (bf16)(v1.z * rs * w1.z), (bf16)(v1.w * rs * w1.w) };
    *(bf16x4*)(yr + t * 4) = o0;
    *(bf16x4*)(yr + 1024 + t * 4) = o1;
}

// ---------------------------------------------------------------------------
// Fused Q + KV projections. (unchanged from R5/R7 — deep-pipeline 8-phase)
// ---------------------------------------------------------------------------
__global__ __launch_bounds__(512, 2) void proj_all(
    const bf16* __restrict__ hb, const bf16* __restrict__ kvb,
    const bf16* __restrict__ WqT, const bf16* __restrict__ WkvT,
    bf16* __restrict__ qb, bf16* __restrict__ kb, bf16* __restrict__ vtb)
{
    __shared__ __align__(16) bf16 smem[4][16384];   // EA,EB,OA,OB = 128 KiB
    bf16* const EA = smem[0]; bf16* const EB = smem[1];
    bf16* const OA = smem[2]; bf16* const OB = smem[3];

    const int id0 = blockIdx.x;
    const int id = (id0 & 7) * 26 + (id0 >> 3);     // bijective: 208 = 8*26
    const bf16 *A, *B; int m0, n0; bool isQ;
    if (id < 128) {
        isQ = true;  A = hb;  B = WqT;
        m0 = (id >> 3) * 256; n0 = (id & 7) * 256;
    } else {
        const int kd = id - 128;
        isQ = false; A = kvb; B = WkvT;
        m0 = (kd >> 4) * 256; n0 = (kd & 15) * 256;
    }

    const int tid = threadIdx.x, lane = tid & 63, w = tid >> 6;
    const int wm = (w >> 2) * 128, wn = (w & 3) * 64;
    const int fr = lane & 15, fg = lane >> 4;

    f32x4 acc[8][4] = {};
    bf16x8 af[4][2], bg[4][2];

    const int aoff0 = (wm + fr) * 64 + (fg ^ (fr & 7)) * 8;
    const int boff0 = (wn + fr) * 64 + (fg ^ (fr & 7)) * 8;
    const int aoff1 = aoff0 ^ 32, boff1 = boff0 ^ 32;
    const bf16* const pAE[2] = { EA + aoff0, EA + aoff1 };
    const bf16* const pAO[2] = { OA + aoff0, OA + aoff1 };
    const bf16* const pBE[2] = { EB + boff0, EB + boff1 };
    const bf16* const pBO[2] = { OB + boff0, OB + boff1 };

    const long toff = (long)(tid >> 3) * 2048 + (((tid & 7) ^ ((tid >> 3) & 7)) * 8);
    const bf16* const gA0 = A + (long)m0 * 2048 + toff;
    const bf16* const gA1 = gA0 + 262144;           // +128 rows
    const bf16* const gB0 = B + (long)n0 * 2048 + toff;
    const bf16* const gB1 = gB0 + 262144;
    bf16* const dT = (bf16*)smem + tid * 8;

    auto stage2 = [&](const bf16* g, int k, int dslot) {
        gld_lds16(g + k, dT + dslot);
        gld_lds16(g + 131072 + k, dT + dslot + 4096);
    };
    enum { sEA0 = 0, sEA1 = 8192, sEB0 = 16384, sEB1 = 24576,
           sOA0 = 32768, sOA1 = 40960, sOB0 = 49152, sOB1 = 57344 };

    auto load_af = [&](const bf16* const p[2], int ib) {
#pragma unroll
        for (int i = 0; i < 4; ++i)
#pragma unroll
            for (int s = 0; s < 2; ++s)
                af[i][s] = *(const bf16x8*)(p[s] + (ib + i) * 1024);
    };
    auto load_bg4 = [&](const bf16* const p[2]) {
#pragma unroll
        for (int j = 0; j < 4; ++j)
#pragma unroll
            for (int s = 0; s < 2; ++s)
                bg[j][s] = *(const bf16x8*)(p[s] + j * 1024);
    };
    auto mfma16 = [&](int ib, int jb) {
        __builtin_amdgcn_s_setprio(1);
#pragma unroll
        for (int s = 0; s < 2; ++s)
#pragma unroll
            for (int i = 0; i < 4; ++i)
#pragma unroll
                for (int j = 0; j < 2; ++j)
                    acc[ib + i][jb + j] = __builtin_amdgcn_mfma_f32_16x16x32_bf16(
                        af[i][s], bg[jb + j][s], acc[ib + i][jb + j], 0, 0, 0);
        __builtin_amdgcn_s_setprio(0);
    };

    stage2(gA0, 0, sEA0); stage2(gA1, 0, sEA1);
    stage2(gB0, 0, sEB0); stage2(gB1, 0, sEB1);
    stage2(gB0, 64, sOB0); stage2(gB1, 64, sOB1);
    stage2(gA0, 64, sOA0);
    VMCNT(6);
    PH_BARRIER();

    for (int it = 0; it < 15; ++it) {
        const int kO = it * 128 + 64, kE2 = it * 128 + 128, kO2 = it * 128 + 192;
        load_af(pAE, 0); load_bg4(pBE);
        stage2(gA1, kO, sOA1);
        PH_BARRIER(); mfma16(0, 0); PH_BARRIER();
        stage2(gB0, kE2, sEB0);
        PH_BARRIER(); mfma16(0, 2); PH_BARRIER();
        load_af(pAE, 4);
        stage2(gB1, kE2, sEB1);
        PH_BARRIER(); mfma16(4, 2); PH_BARRIER();
        stage2(gA0, kE2, sEA0);
        PH_BARRIER(); mfma16(4, 0); VMCNT(6); PH_BARRIER();
        load_af(pAO, 0); load_bg4(pBO);
        stage2(gA1, kE2, sEA1);
        PH_BARRIER(); mfma16(0, 0); PH_BARRIER();
        stage2(gB0, kO2, sOB0);
        PH_BARRIER(); mfma16(0, 2); PH_BARRIER();
        load_af(pAO, 4);
        stage2(gB1, kO2, sOB1);
        PH_BARRIER(); mfma16(4, 2); PH_BARRIER();
        stage2(gA0, kO2, sOA0);
        PH_BARRIER(); mfma16(4, 0); VMCNT(6); PH_BARRIER();
    }
    {
        load_af(pAE, 0); load_bg4(pBE);
        stage2(gA1, 1984, sOA1);
        PH_BARRIER(); mfma16(0, 0); PH_BARRIER();
        PH_BARRIER(); mfma16(0, 2); PH_BARRIER();
        load_af(pAE, 4);
        PH_BARRIER(); mfma16(4, 2); PH_BARRIER();
        PH_BARRIER(); mfma16(4, 0); VMCNT(0); PH_BARRIER();
        load_af(pAO, 0); load_bg4(pBO);
        PH_BARRIER(); mfma16(0, 0); PH_BARRIER();
        PH_BARRIER(); mfma16(0, 2); PH_BARRIER();
        load_af(pAO, 4);
        PH_BARRIER(); mfma16(4, 2); PH_BARRIER();
        PH_BARRIER(); mfma16(4, 0); PH_BARRIER();
    }

    __syncthreads();

    const int er = fg * 4;
    if (isQ || n0 < 2048) {
        bf16* C = isQ ? qb : kb;
        const int mlim = isQ ? 4096 : 1152;
#pragma unroll
        for (int i = 0; i < 8; ++i)
#pragma unroll
            for (int j = 0; j < 4; ++j) {
                const int n = n0 + wn + j * 16 + fr;
#pragma unroll
                for (int r = 0; r < 4; ++r) {
                    const int m = m0 + wm + i * 16 + er + r;
                    if (m < mlim)
                        C[(long)m * 2048 + n] = (bf16)acc[i][j][r];
                }
            }
        return;
    }

    bf16* T = &smem[0][0];                 // [128][264]
#pragma unroll
    for (int p2 = 0; p2 < 2; ++p2) {
        if (p2) __syncthreads();
        if ((wn >> 7) == p2) {
            const int nb = wn - p2 * 128;
#pragma unroll
            for (int i = 0; i < 8; ++i)
#pragma unroll
                for (int j = 0; j < 4; ++j) {
                    const int nl = nb + j * 16 + fr;
#pragma unroll
                    for (int r = 0; r < 4; ++r)
                        T[nl * 264 + wm + i * 16 + er + r] = (bf16)acc[i][j][r];
                }
        }
        __syncthreads();
        const int hh = (n0 - 2048 + p2 * 128) >> 7;
        for (int e = tid; e < 128 * 64; e += 512) {
            const int d = e >> 6, mg = (e & 63) * 4;
            const int mm = m0 + mg;
            if (mm < 1152) {
                bf16x4 val = *(const bf16x4*)(T + d * 264 + mg);
                const int bb = mm >= NKV;
                const int s = mm - bb * NKV;
                *(bf16x4*)(vtb + ((long)((bb * 16 + hh) * 128 + d)) * NKV + s) = val;
            }
        }
    }
}

// ---------------------------------------------------------------------------
// Final GEMM: out(4096x2048 fp32) = aob @ WoT^T. (unchanged from R5/R7)
// ---------------------------------------------------------------------------
__global__ __launch_bounds__(512, 2) void gemm_final(
    const bf16* __restrict__ Ag, const bf16* __restrict__ Bg, float* __restrict__ C)
{
    __shared__ __align__(16) bf16 smem[49152];
    bf16* const EA = smem;           bf16* const EB = smem + 16384;
    bf16* const OA = smem + 24576;   bf16* const OB = smem + 40960;

    const int id0 = blockIdx.x;
    const int id = (id0 & 7) * 32 + (id0 >> 3);    // 256 = 8*32
    const int m0 = (id >> 4) * 256, n0 = (id & 15) * 128;

    const int tid = threadIdx.x, lane = tid & 63, w = tid >> 6;
    const int wm = (w >> 1) * 64, wn = (w & 1) * 64;
    const int fr = lane & 15, fg = lane >> 4;

    f32x4 acc[4][4] = {};
    bf16x8 af[2][2], bg[4][2];

    const int aoff0 = (wm + fr) * 64 + (fg ^ (fr & 7)) * 8;
    const int boff0 = (wn + fr) * 64 + (fg ^ (fr & 7)) * 8;
    const int aoff1 = aoff0 ^ 32, boff1 = boff0 ^ 32;
    const bf16* const pAE[2] = { EA + aoff0, EA + aoff1 };
    const bf16* const pAO[2] = { OA + aoff0, OA + aoff1 };
    const bf16* const pBE[2] = { EB + boff0, EB + boff1 };
    const bf16* const pBO[2] = { OB + boff0, OB + boff1 };

    const long toff = (long)(tid >> 3) * 2048 + (((tid & 7) ^ ((tid >> 3) & 7)) * 8);
    const bf16* const gA0 = Ag + (long)m0 * 2048 + toff;
    const bf16* const gA1 = gA0 + 262144;
    const bf16* const gB0 = Bg + (long)n0 * 2048 + toff;
    bf16* const dT = smem + tid * 8;

    auto stage2 = [&](const bf16* g, int k, int dslot) {
        gld_lds16(g + k, dT + dslot);
        gld_lds16(g + 131072 + k, dT + dslot + 4096);
    };
    enum { sEA0 = 0, sEA1 = 8192, sEB0 = 16384,
           sOA0 = 24576, sOA1 = 32768, sOB0 = 40960 };

    auto load_af = [&](const bf16* const p[2], int ib) {
#pragma unroll
        for (int i = 0; i < 2; ++i)
#pragma unroll
            for (int s = 0; s < 2; ++s)
                af[i][s] = *(const bf16x8*)(p[s] + (ib + i) * 1024);
    };
    auto load_bg4 = [&](const bf16* const p[2]) {
#pragma unroll
        for (int j = 0; j < 4; ++j)
#pragma unroll
            for (int s = 0; s < 2; ++s)
                bg[j][s] = *(const bf16x8*)(p[s] + j * 1024);
    };
    auto mfma8 = [&](int ib, int jb) {
        __builtin_amdgcn_s_setprio(1);
#pragma unroll
        for (int s = 0; s < 2; ++s)
#pragma unroll
            for (int i = 0; i < 2; ++i)
#pragma unroll
                for (int j = 0; j < 2; ++j)
                    acc[ib + i][jb + j] = __builtin_amdgcn_mfma_f32_16x16x32_bf16(
                        af[i][s], bg[jb + j][s], acc[ib + i][jb + j], 0, 0, 0);
        __builtin_amdgcn_s_setprio(0);
    };

    stage2(gA0, 0, sEA0); stage2(gA1, 0, sEA1);
    stage2(gB0, 0, sEB0);
    stage2(gB0, 64, sOB0); stage2(gA0, 64, sOA0);
    VMCNT(4);
    PH_BARRIER();

    for (int it = 0; it < 15; ++it) {
        const int kO = it * 128 + 64, kE2 = it * 128 + 128, kO2 = it * 128 + 192;
        load_af(pAE, 0); load_bg4(pBE);
        stage2(gA1, kO, sOA1);
        PH_BARRIER(); mfma8(0, 0); PH_BARRIER();
        stage2(gB0, kE2, sEB0);
        PH_BARRIER(); mfma8(0, 2); PH_BARRIER();
        load_af(pAE, 2);
        PH_BARRIER(); mfma8(2, 2); PH_BARRIER();
        stage2(gA0, kE2, sEA0);
        PH_BARRIER(); mfma8(2, 0); VMCNT(4); PH_BARRIER();
        load_af(pAO, 0); load_bg4(pBO);
        stage2(gA1, kE2, sEA1);
        PH_BARRIER(); mfma8(0, 0); PH_BARRIER();
        stage2(gB0, kO2, sOB0);
        PH_BARRIER(); mfma8(0, 2); PH_BARRIER();
        load_af(pAO, 2);
        PH_BARRIER(); mfma8(2, 2); PH_BARRIER();
        stage2(gA0, kO2, sOA0);
        PH_BARRIER(); mfma8(2, 0); VMCNT(4); PH_BARRIER();
    }
    {
        load_af(pAE, 0); load_bg4(pBE);
        stage2(gA1, 1984, sOA1);
        PH_BARRIER(); mfma8(0, 0); PH_BARRIER();
        PH_BARRIER(); mfma8(0, 2); PH_BARRIER();
        load_af(pAE, 2);
        PH_BARRIER(); mfma8(2, 2); PH_BARRIER();
        PH_BARRIER(); mfma8(2, 0); VMCNT(0); PH_BARRIER();
        load_af(pAO, 0); load_bg4(pBO);
        PH_BARRIER(); mfma8(0, 0); PH_BARRIER();
        PH_BARRIER(); mfma8(0, 2); PH_BARRIER();
        load_af(pAO, 2);
        PH_BARRIER(); mfma8(2, 2); PH_BARRIER();
        PH_BARRIER(); mfma8(2, 0); PH_BARRIER();
    }

    __syncthreads();

    const int er = fg * 4;
#pragma unroll
    for (int i = 0; i < 4; ++i)
#pragma unroll
        for (int j = 0; j < 4; ++j) {
            const int n = n0 + wn + j * 16 + fr;
#pragma unroll
            for (int r = 0; r < 4; ++r)
                C[(long)(m0 + wm + i * 16 + er + r) * 2048 + n] = acc[i][j][r];
        }
}

// ---------------------------------------------------------------------------
// Flash attention: 8 waves, q-tile 128, kv-chunk 64 (9 chunks). R7 structure
// (single-buffer Ks/VTs + dedicated Ps, 50 KiB LDS) + T14 async-STAGE split:
// chunk kc+1's 4 global_load_dwordx4 issue at the TOP of chunk kc's compute
// (HBM latency hides under QK^T+softmax+PV); the ds_writes happen after the
// barrier that retires chunk kc's reads. No exposed load latency, LDS and
// barrier count unchanged vs R7. grid (T/128, H, B) = (16,16,2).
// ---------------------------------------------------------------------------
__global__ __launch_bounds__(512, 4) void flash_attn(
    const bf16* __restrict__ Q, const bf16* __restrict__ K,
    const bf16* __restrict__ VT, const int* __restrict__ cmask,
    bf16* __restrict__ O)
{
    __shared__ __align__(16) bf16 Ks[64 * 128];   // swizzled K chunk (16 KB)
    __shared__ __align__(16) bf16 VTs[128 * 64];  // swizzled V^T chunk (16 KB)
    __shared__ __align__(16) bf16 Ps[128 * 72];   // P transpose, per-wave rows (18 KB)

    const int qt = blockIdx.x, h = blockIdx.y, b = blockIdx.z;
    const int tid = threadIdx.x, lane = tid & 63, w = tid >> 6;   // w: 0..7
    const int fr = lane & 15, fg = lane >> 4;

    const bf16* qbase = Q + ((long)(b * 2048 + qt * 128)) * 2048 + h * 128;
    bf16x8 qf[4];
#pragma unroll
    for (int s = 0; s < 4; ++s)
        qf[s] = *(const bf16x8*)(qbase + (long)(w * 16 + fr) * 2048 + s * 32 + fg * 8);

    float m_r[4], l_r[4];
    f32x4 acc_o[8];
#pragma unroll
    for (int r = 0; r < 4; ++r) { m_r[r] = -3.0e38f; l_r[r] = 0.f; }
#pragma unroll
    for (int j = 0; j < 8; ++j) acc_o[j] = (f32x4){0.f, 0.f, 0.f, 0.f};

    const float scale2 = 0.12752792330124195f;  // (1/sqrt(128)) * log2(e)
    const bf16* kbase = K + (long)b * NKV * 2048 + h * 128;
    const bf16* vbase = VT + ((long)(b * 16 + h)) * 128 * NKV;
    const int* const cm = cmask + b * 512;

    // T14 reg-staging: same pre-swizzled global sources / linear LDS dests
    // as the R7 global_load_lds version, so the read paths are unchanged.
    bf16x8 kreg[2], vreg[2];
    auto loadKV = [&](int kv0) {
#pragma unroll
        for (int p = 0; p < 2; ++p) {
            const int c = p * 512 + tid;
            const int rk = c >> 4, clk = (c & 15) ^ (rk & 15);
            kreg[p] = *(const bf16x8*)(kbase + (long)(kv0 + rk) * 2048 + clk * 8);
            const int rv = c >> 3, clv = (c & 7) ^ (rv & 7);
            vreg[p] = *(const bf16x8*)(vbase + (long)rv * NKV + kv0 + clv * 8);
        }
    };
    auto storeKV = [&]() {
#pragma unroll
        for (int p = 0; p < 2; ++p) {
            *(bf16x8*)(Ks + (p * 512 + tid) * 8) = kreg[p];
            *(bf16x8*)(VTs + (p * 512 + tid) * 8) = vreg[p];
        }
    };

    // prologue: chunk 0 through registers (load -> store -> barrier)
    loadKV(0);
    storeKV();
    __syncthreads();

    for (int kc = 0; kc < 9; ++kc) {
        const int kv0 = kc * 64;
        // issue next chunk's loads NOW — latency hides under this chunk's compute
        if (kc < 8) loadKV(kv0 + 64);

        f32x4 acc_s[4] = {};
#pragma unroll
        for (int s = 0; s < 4; ++s) {
#pragma unroll
            for (int j = 0; j < 4; ++j) {
                bf16x8 bgv = *(const bf16x8*)(Ks +
                    ((j * 16 + fr) * 16 + ((s * 4 + fg) ^ fr)) * 8);
                acc_s[j] = __builtin_amdgcn_mfma_f32_16x16x32_bf16(qf[s], bgv, acc_s[j], 0, 0, 0);
            }
        }

        float bias[4];
#pragma unroll
        for (int j = 0; j < 4; ++j) {
            const int kv = kv0 + j * 16 + fr;
            const bool valid = (kv < 64) || (cm[kv - 64] != 0);
            bias[j] = valid ? 0.f : -1e30f;
        }
        float s_f[4][4];
        float mc[4] = {-3.0e38f, -3.0e38f, -3.0e38f, -3.0e38f};
#pragma unroll
        for (int j = 0; j < 4; ++j)
#pragma unroll
            for (int r = 0; r < 4; ++r) {
                float v = fmaf(acc_s[j][r], scale2, bias[j]);
                s_f[j][r] = v; mc[r] = fmaxf(mc[r], v);
            }
#pragma unroll
        for (int r = 0; r < 4; ++r) {
            mc[r] = fmaxf(mc[r], __shfl_xor(mc[r], 1));
            mc[r] = fmaxf(mc[r], __shfl_xor(mc[r], 2));
            mc[r] = fmaxf(mc[r], __shfl_xor(mc[r], 4));
            mc[r] = fmaxf(mc[r], __shfl_xor(mc[r], 8));
        }
        float alpha[4];
#pragma unroll
        for (int r = 0; r < 4; ++r) {
            const float mn = fmaxf(m_r[r], mc[r]);
            alpha[r] = __builtin_amdgcn_exp2f(m_r[r] - mn);
            m_r[r] = mn;
        }
        float rs[4] = {0.f, 0.f, 0.f, 0.f};
#pragma unroll
        for (int j = 0; j < 4; ++j)
#pragma unroll
            for (int r = 0; r < 4; ++r) {
                const float pv = __builtin_amdgcn_exp2f(s_f[j][r] - m_r[r]);
                s_f[j][r] = pv; rs[r] += pv;
            }
#pragma unroll
        for (int r = 0; r < 4; ++r) {
            rs[r] += __shfl_xor(rs[r], 1);
            rs[r] += __shfl_xor(rs[r], 2);
            rs[r] += __shfl_xor(rs[r], 4);
            rs[r] += __shfl_xor(rs[r], 8);
            l_r[r] = l_r[r] * alpha[r] + rs[r];
        }
#pragma unroll
        for (int j = 0; j < 8; ++j)
#pragma unroll
            for (int r = 0; r < 4; ++r) acc_o[j][r] *= alpha[r];

        // P transpose through dedicated Ps (per-wave rows; in-order DS, no barrier)
#pragma unroll
        for (int j = 0; j < 4; ++j)
#pragma unroll
            for (int r = 0; r < 4; ++r)
                Ps[(w * 16 + fg * 4 + r) * 72 + j * 16 + fr] = (bf16)s_f[j][r];

#pragma unroll
        for (int s2 = 0; s2 < 2; ++s2) {
            bf16x8 afv = *(const bf16x8*)(Ps + (w * 16 + fr) * 72 + s2 * 32 + fg * 8);
#pragma unroll
            for (int jd = 0; jd < 8; ++jd) {
                bf16x8 bgv = *(const bf16x8*)(VTs +
                    ((jd * 16 + fr) * 8 + ((s2 * 4 + fg) ^ (fr & 7))) * 8);
                acc_o[jd] = __builtin_amdgcn_mfma_f32_16x16x32_bf16(afv, bgv, acc_o[jd], 0, 0, 0);
            }
        }

        __syncthreads();                 // (c) K/VT reads of chunk kc done
        if (kc < 8) {
            storeKV();                   // regs ready (loads issued a chunk ago)
            __syncthreads();             // (a) staging visible for chunk kc+1
        }
    }

    bf16* obase = O + ((long)(b * 2048 + qt * 128)) * 2048 + h * 128;
#pragma unroll
    for (int r = 0; r < 4; ++r) {
        const float inv = 1.0f / l_r[r];
        const int row = w * 16 + fg * 4 + r;
#pragma unroll
        for (int jd = 0; jd < 8; ++jd)
            obase[(long)row * 2048 + jd * 16 + fr] = (bf16)(acc_o[jd][r] * inv);
    }
}

// ---------------------------------------------------------------------------
extern "C" void kernel_launch(void* const* d_in, const int* in_sizes, int n_in,
                              void* d_out, int out_size, void* d_ws, size_t ws_size,
                              hipStream_t stream)
{
    const float* hidden = (const float*)d_in[0];
    const float* wsp    = (const float*)d_in[1];
    const float* corr   = (const float*)d_in[2];
    const int*   cmask  = (const int*)d_in[3];
    const float* lnq    = (const float*)d_in[4];
    const float* lnkv   = (const float*)d_in[5];
    const float* Wq     = (const float*)d_in[6];
    const float* Wk     = (const float*)d_in[7];
    const float* Wv     = (const float*)d_in[8];
    const float* Wo     = (const float*)d_in[9];
    float* out = (float*)d_out;

    char* ws = (char*)d_ws;
    size_t off = 0;
    auto alloc = [&](size_t sz) { void* p = ws + off; off += (sz + 255) & ~(size_t)255; return p; };

    bf16* WqT   = (bf16*)alloc(2048ull * 2048 * 2);
    bf16* WkvT  = (bf16*)alloc(4096ull * 2048 * 2);   // [WkT ; WvT]
    bf16* WoT   = (bf16*)alloc(2048ull * 2048 * 2);
    bf16* hb    = (bf16*)alloc(4096ull * 2048 * 2);
    bf16* kvb   = (bf16*)alloc(1280ull * 2048 * 2);   // padded to 1280 rows
    bf16* qb    = (bf16*)alloc(4096ull * 2048 * 2);
    bf16* kb    = (bf16*)alloc(1152ull * 2048 * 2);   // K (B,576,2048)
    bf16* vtb   = (bf16*)alloc(4096ull * NKV * 2);    // V^T (B,H,128,576)
    bf16* aob   = (bf16*)alloc(4096ull * 2048 * 2);

    prep<<<9344, 256, 0, stream>>>(hidden, wsp, corr, lnq, lnkv,
                                   Wq, Wk, Wv, Wo, hb, kvb, WqT, WkvT, WoT);
    proj_all<<<208, 512, 0, stream>>>(hb, kvb, WqT, WkvT, qb, kb, vtb);
    flash_attn<<<dim3(16, 16, 2), 512, 0, stream>>>(qb, kb, vtb, cmask, aob);
    gemm_final<<<256, 512, 0, stream>>>(aob, WoT, out);
}